// Round 3
// baseline (148.798 us; speedup 1.0000x reference)
//
#include <hip/hip_runtime.h>

#define B_   8
#define C_   512
#define HW_  1024
#define MID_ 64
#define NCOL (B_*HW_)   /* 8192 */
#define NROWS 192
#define EPS  1e-5f

/* ws layout (float offsets) */
#define YOFF  0
#define YSZ   (NROWS*NCOL)            /* 1,572,864 f32 */
#define SSOFF (YOFF+YSZ)              /* scaleF[64] shiftF[64] scaleG[64] shiftG[64] */
#define SSSZ  256
#define WOFF  (SSOFF+SSSZ)            /* Whi[192*512]u16, Wlo[192*512]u16 = 98,304 floats */
#define WSZ   98304
#define CPOFF (WOFF+WSZ)              /* partials [8][3][nchunk][64][64] f32 */
/* isoff = CPOFF + 8*3*nchunk*4096 ; uoff = isoff + 16 (computed per nchunk) */

typedef unsigned short u16;
typedef __attribute__((ext_vector_type(8))) short short8;
typedef __attribute__((ext_vector_type(4))) float f32x4;

__device__ __forceinline__ u16 f2bf(float f) {
  unsigned u = __float_as_uint(f);
  unsigned r = u + 0x7fffu + ((u >> 16) & 1u);
  return (u16)(r >> 16);
}
__device__ __forceinline__ float bf2f(u16 h) {
  return __uint_as_float(((unsigned)h) << 16);
}
#define MFMA_B16(a,b,c) __builtin_amdgcn_mfma_f32_16x16x32_bf16(a,b,c,0,0,0)

/* ---- split W = [Wf;Wg;Wh] (192x512) into bf16 hi/lo in ws ---- */
__global__ __launch_bounds__(256) void k_prep(
    const float* __restrict__ Wf, const float* __restrict__ Wg,
    const float* __restrict__ Wh, float* __restrict__ ws)
{
  u16* Whi = (u16*)(ws + WOFF);
  u16* Wlo = Whi + NROWS*C_;
  const int e4 = blockIdx.x*256 + threadIdx.x;   /* 0..24575 */
  const int e  = e4*4;
  const int row = e >> 9, k = e & 511;
  const float* src = (row < 64) ? &Wf[row*C_ + k]
                   : (row < 128) ? &Wg[(row-64)*C_ + k]
                   : &Wh[(row-128)*C_ + k];
  const float4 v = *reinterpret_cast<const float4*>(src);
  u16 h0=f2bf(v.x), h1=f2bf(v.y), h2=f2bf(v.z), h3=f2bf(v.w);
  u16 l0=f2bf(v.x-bf2f(h0)), l1=f2bf(v.y-bf2f(h1)), l2=f2bf(v.z-bf2f(h2)), l3=f2bf(v.w-bf2f(h3));
  uint2 ph; ph.x = (unsigned)h0 | ((unsigned)h1<<16); ph.y = (unsigned)h2 | ((unsigned)h3<<16);
  uint2 pl; pl.x = (unsigned)l0 | ((unsigned)l1<<16); pl.y = (unsigned)l2 | ((unsigned)l3<<16);
  *reinterpret_cast<uint2*>(&Whi[e]) = ph;
  *reinterpret_cast<uint2*>(&Wlo[e]) = pl;
}

/* ---- Y[192][8192] = W @ X + bias, MFMA bf16x3 split ----
   grid: 256 blocks (32-col tiles), 256 thr (4 waves); wave w owns rows w*48..w*48+47 */
__global__ __launch_bounds__(256) void k_conv(
    const float* __restrict__ x,
    const float* __restrict__ bf, const float* __restrict__ bg, const float* __restrict__ bh,
    float* __restrict__ ws)
{
  __shared__ u16 Xh[8*32*8];   /* [kg][c][i] : x[kk+kg*8+i][n0+c] hi */
  __shared__ u16 Xl[8*32*8];
  const u16* Whi = (const u16*)(ws + WOFF);
  const u16* Wlo = Whi + NROWS*C_;
  const int n0  = blockIdx.x * 32;
  const int b   = n0 >> 10;
  const int hw0 = n0 & 1023;
  const int t   = threadIdx.x;
  const int lane = t & 63;
  const int wid  = t >> 6;
  const int wrow0 = wid * 48;
  const int cst  = t & 31;         /* staging col */
  const int kg2  = t >> 5;         /* staging k-group 0..7 */
  const int lm   = lane & 15;
  const int lk   = lane >> 4;

  f32x4 acc[3][2];
  #pragma unroll
  for (int i=0;i<3;++i) { acc[i][0]=(f32x4)0.f; acc[i][1]=(f32x4)0.f; }

  for (int kk = 0; kk < C_; kk += 64) {
    __syncthreads();
    /* stage: 8 k-rows per thread, coalesced across cst */
    {
      const float* xp = x + ((size_t)(b*C_ + kk + kg2*8))*HW_ + hw0 + cst;
      u16 hb[8], lb[8];
      #pragma unroll
      for (int i=0;i<8;++i) {
        const float v = xp[(size_t)i*HW_];
        hb[i] = f2bf(v); lb[i] = f2bf(v - bf2f(hb[i]));
      }
      uint4 ph, pl;
      ph.x=(unsigned)hb[0]|((unsigned)hb[1]<<16); ph.y=(unsigned)hb[2]|((unsigned)hb[3]<<16);
      ph.z=(unsigned)hb[4]|((unsigned)hb[5]<<16); ph.w=(unsigned)hb[6]|((unsigned)hb[7]<<16);
      pl.x=(unsigned)lb[0]|((unsigned)lb[1]<<16); pl.y=(unsigned)lb[2]|((unsigned)lb[3]<<16);
      pl.z=(unsigned)lb[4]|((unsigned)lb[5]<<16); pl.w=(unsigned)lb[6]|((unsigned)lb[7]<<16);
      *reinterpret_cast<uint4*>(&Xh[(kg2*32+cst)*8]) = ph;
      *reinterpret_cast<uint4*>(&Xl[(kg2*32+cst)*8]) = pl;
    }
    __syncthreads();
    #pragma unroll
    for (int kb = 0; kb < 2; ++kb) {
      short8 bhf[2], blf[2];
      #pragma unroll
      for (int nt = 0; nt < 2; ++nt) {
        const int col = nt*16 + lm;
        const int idx = ((kb*4 + lk)*32 + col)*8;
        bhf[nt] = *reinterpret_cast<const short8*>(&Xh[idx]);
        blf[nt] = *reinterpret_cast<const short8*>(&Xl[idx]);
      }
      #pragma unroll
      for (int mt = 0; mt < 3; ++mt) {
        const int row = wrow0 + mt*16 + lm;
        const size_t widx = (size_t)row*C_ + kk + kb*32 + lk*8;
        const short8 ah = *reinterpret_cast<const short8*>(&Whi[widx]);
        const short8 al = *reinterpret_cast<const short8*>(&Wlo[widx]);
        #pragma unroll
        for (int nt = 0; nt < 2; ++nt) {
          acc[mt][nt] = MFMA_B16(ah, bhf[nt], acc[mt][nt]);
          acc[mt][nt] = MFMA_B16(al, bhf[nt], acc[mt][nt]);
          acc[mt][nt] = MFMA_B16(ah, blf[nt], acc[mt][nt]);
        }
      }
    }
  }
  /* epilogue: + bias, store Y f32 */
  #pragma unroll
  for (int mt = 0; mt < 3; ++mt) {
    const int rbase = wrow0 + mt*16;
    const float* bp = (rbase < 64) ? bf : (rbase < 128) ? bg : bh;
    const int rloc0 = (rbase & 63) + lk*4;
    #pragma unroll
    for (int nt = 0; nt < 2; ++nt) {
      const int col = n0 + nt*16 + lm;
      #pragma unroll
      for (int r = 0; r < 4; ++r) {
        const int row = rbase + lk*4 + r;
        ws[YOFF + (size_t)row*NCOL + col] = acc[mt][nt][r] + bp[rloc0 + r];
      }
    }
  }
}

/* per-row mean/var over 8192 cols for rows 0..127, fold BN into scale/shift */
__global__ __launch_bounds__(256) void k_stats(
    const float* __restrict__ gamma_f, const float* __restrict__ beta_f,
    const float* __restrict__ gamma_g, const float* __restrict__ beta_g,
    float* __restrict__ ws)
{
  const int r = blockIdx.x;   /* 0..127 */
  const float4* Yr = reinterpret_cast<const float4*>(ws + YOFF + (size_t)r*NCOL);
  const int t = threadIdx.x;
  float s = 0.f, s2 = 0.f;
  for (int n = t; n < NCOL/4; n += 256) {
    const float4 v = Yr[n];
    s  += (v.x+v.y)+(v.z+v.w);
    s2 += (v.x*v.x+v.y*v.y)+(v.z*v.z+v.w*v.w);
  }
  __shared__ float sh[256], sh2[256];
  sh[t] = s; sh2[t] = s2;
  __syncthreads();
  for (int st = 128; st > 0; st >>= 1) {
    if (t < st) { sh[t] += sh[t+st]; sh2[t] += sh2[t+st]; }
    __syncthreads();
  }
  if (t == 0) {
    const float mean = sh[0] * (1.0f/NCOL);
    const float var  = sh2[0] * (1.0f/NCOL) - mean*mean;
    float g, be; int j;
    if (r < 64) { j = r;     g = gamma_f[j]; be = beta_f[j]; }
    else        { j = r-64;  g = gamma_g[j]; be = beta_g[j]; }
    const float sc = g * rsqrtf(var + EPS);
    const float sf = be - mean*sc;
    if (r < 64) { ws[SSOFF + j]       = sc; ws[SSOFF + 64  + j] = sf; }
    else        { ws[SSOFF + 128 + j] = sc; ws[SSOFF + 192 + j] = sf; }
  }
}

/* ---- fused Cf/Cg/T partials via MFMA bf16x3.
   grid (nchunk, B_), 256 thr. Stages F,G,H (BN+relu for F,G) for a 64-col step,
   computes all three 64x64 products. LDS rows padded +8 u16 (16B) -> conflict-free. */
__global__ __launch_bounds__(256) void k_cpart(float* __restrict__ ws, int nchunk)
{
  __shared__ u16 Sh[3][64][72];
  __shared__ u16 Sl[3][64][72];
  const int chunk = blockIdx.x, b = blockIdx.y;
  const int chunkcols = 1024 / nchunk;
  const int bcol0 = b*1024 + chunk*chunkcols;
  const float* Y = ws + YOFF;
  const float* SS = ws + SSOFF;
  const int t = threadIdx.x;
  const int lane = t & 63, wid = t >> 6;
  const int lm = lane & 15, lk = lane >> 4;
  const int mt0 = (wid >> 1) * 2;   /* wave's m-tile base (0 or 2) */
  const int nt0 = (wid & 1) * 2;    /* wave's n-tile base (0 or 2) */

  f32x4 acc[3][2][2];
  #pragma unroll
  for (int p=0;p<3;++p) for (int i=0;i<2;++i) for (int j=0;j<2;++j) acc[p][i][j]=(f32x4)0.f;

  for (int kk = 0; kk < chunkcols; kk += 64) {
    __syncthreads();
    for (int q = t; q < 3072; q += 256) {
      const int mm = q >> 10, rem = q & 1023;
      const int r = rem >> 4, c4 = (rem & 15) * 4;
      const float4 v = *reinterpret_cast<const float4*>(
          &Y[(size_t)(mm*64 + r)*NCOL + bcol0 + kk + c4]);
      float v0, v1, v2, v3;
      if (mm < 2) {
        const float sc = SS[mm*128 + r], sf = SS[mm*128 + 64 + r];
        v0 = fmaxf(sc*v.x+sf, 0.f); v1 = fmaxf(sc*v.y+sf, 0.f);
        v2 = fmaxf(sc*v.z+sf, 0.f); v3 = fmaxf(sc*v.w+sf, 0.f);
      } else { v0=v.x; v1=v.y; v2=v.z; v3=v.w; }
      const u16 h0=f2bf(v0), h1=f2bf(v1), h2=f2bf(v2), h3=f2bf(v3);
      uint2 ph; ph.x=(unsigned)h0|((unsigned)h1<<16); ph.y=(unsigned)h2|((unsigned)h3<<16);
      uint2 pl;
      pl.x=(unsigned)f2bf(v0-bf2f(h0)) | ((unsigned)f2bf(v1-bf2f(h1))<<16);
      pl.y=(unsigned)f2bf(v2-bf2f(h2)) | ((unsigned)f2bf(v3-bf2f(h3))<<16);
      *reinterpret_cast<uint2*>(&Sh[mm][r][c4]) = ph;
      *reinterpret_cast<uint2*>(&Sl[mm][r][c4]) = pl;
    }
    __syncthreads();
    #pragma unroll
    for (int kb = 0; kb < 2; ++kb) {
      const int ko = kb*32 + lk*8;
      short8 ah[3][2], al[3][2];   /* A frags: mats F,G,H x 2 m-tiles */
      #pragma unroll
      for (int m = 0; m < 3; ++m)
        #pragma unroll
        for (int mi = 0; mi < 2; ++mi) {
          const int row = (mt0+mi)*16 + lm;
          ah[m][mi] = *reinterpret_cast<const short8*>(&Sh[m][row][ko]);
          al[m][mi] = *reinterpret_cast<const short8*>(&Sl[m][row][ko]);
        }
      short8 bhf[2][2], blf[2][2]; /* B frags: mats F,G x 2 n-tiles */
      #pragma unroll
      for (int m = 0; m < 2; ++m)
        #pragma unroll
        for (int ni = 0; ni < 2; ++ni) {
          const int row = (nt0+ni)*16 + lm;
          bhf[m][ni] = *reinterpret_cast<const short8*>(&Sh[m][row][ko]);
          blf[m][ni] = *reinterpret_cast<const short8*>(&Sl[m][row][ko]);
        }
      #pragma unroll
      for (int p = 0; p < 3; ++p) {
        const int am = p;              /* A: F,G,H */
        const int bm = (p==0) ? 0 : 1; /* B: F,G,G */
        #pragma unroll
        for (int mi = 0; mi < 2; ++mi)
          #pragma unroll
          for (int ni = 0; ni < 2; ++ni) {
            acc[p][mi][ni] = MFMA_B16(ah[am][mi], bhf[bm][ni], acc[p][mi][ni]);
            acc[p][mi][ni] = MFMA_B16(al[am][mi], bhf[bm][ni], acc[p][mi][ni]);
            acc[p][mi][ni] = MFMA_B16(ah[am][mi], blf[bm][ni], acc[p][mi][ni]);
          }
      }
    }
  }
  float* cp = ws + CPOFF;
  #pragma unroll
  for (int p = 0; p < 3; ++p) {
    float* base = cp + ((size_t)((b*3+p)*nchunk + chunk))*4096;
    #pragma unroll
    for (int mi = 0; mi < 2; ++mi)
      #pragma unroll
      for (int ni = 0; ni < 2; ++ni) {
        const int col = (nt0+ni)*16 + lm;
        #pragma unroll
        for (int r = 0; r < 4; ++r) {
          const int row = (mt0+mi)*16 + lk*4 + r;
          base[(size_t)row*64 + col] = acc[p][mi][ni][r];
        }
      }
  }
}

/* per batch: power iteration on M = Cg @ Cf without forming M. */
__global__ __launch_bounds__(64) void k_sigma(float* __restrict__ ws, int nchunk)
{
  const int b = blockIdx.x;
  const int lane = threadIdx.x;
  const float* cp = ws + CPOFF;
  const float* CfP = cp + (size_t)(b*3+0)*nchunk*4096;
  const float* CgP = cp + (size_t)(b*3+1)*nchunk*4096;
  const size_t isoff = (size_t)CPOFF + (size_t)B_*3*nchunk*4096;
  __shared__ float vsh[64];
  __shared__ float ush[64];
  float cfr[64], cgr[64];
  #pragma unroll
  for (int k4 = 0; k4 < 16; ++k4) {
    float ax=0.f, ay=0.f, az=0.f, aw=0.f;
    float cx=0.f, cy=0.f, cz=0.f, cw=0.f;
    for (int ch = 0; ch < nchunk; ++ch) {
      const float4 fa = *reinterpret_cast<const float4*>(&CfP[(size_t)ch*4096 + lane*64 + k4*4]);
      const float4 fc = *reinterpret_cast<const float4*>(&CgP[(size_t)ch*4096 + lane*64 + k4*4]);
      ax+=fa.x; ay+=fa.y; az+=fa.z; aw+=fa.w;
      cx+=fc.x; cy+=fc.y; cz+=fc.z; cw+=fc.w;
    }
    cfr[k4*4+0]=ax; cfr[k4*4+1]=ay; cfr[k4*4+2]=az; cfr[k4*4+3]=aw;
    cgr[k4*4+0]=cx; cgr[k4*4+1]=cy; cgr[k4*4+2]=cz; cgr[k4*4+3]=cw;
  }
  float vloc = 0.125f;
  vsh[lane] = vloc;
  __syncthreads();
  float lambda = 0.f;
  #define NIT 20
  for (int it = 0; it <= NIT; ++it) {
    float u0=0.f,u1=0.f,u2=0.f,u3=0.f;
    #pragma unroll
    for (int j4 = 0; j4 < 16; ++j4) {
      const float4 vq = *reinterpret_cast<const float4*>(&vsh[j4*4]);
      u0 += cfr[j4*4+0]*vq.x; u1 += cfr[j4*4+1]*vq.y;
      u2 += cfr[j4*4+2]*vq.z; u3 += cfr[j4*4+3]*vq.w;
    }
    ush[lane] = (u0+u1)+(u2+u3);
    __syncthreads();
    float w0=0.f,w1=0.f,w2=0.f,w3=0.f;
    #pragma unroll
    for (int j4 = 0; j4 < 16; ++j4) {
      const float4 uq = *reinterpret_cast<const float4*>(&ush[j4*4]);
      w0 += cgr[j4*4+0]*uq.x; w1 += cgr[j4*4+1]*uq.y;
      w2 += cgr[j4*4+2]*uq.z; w3 += cgr[j4*4+3]*uq.w;
    }
    const float w = (w0+w1)+(w2+w3);
    if (it == NIT) {
      float num = vloc * w;
      #pragma unroll
      for (int off = 32; off > 0; off >>= 1) num += __shfl_xor(num, off);
      lambda = num;
    } else {
      float n2 = w*w;
      #pragma unroll
      for (int off = 32; off > 0; off >>= 1) n2 += __shfl_xor(n2, off);
      const float rn = rsqrtf(fmaxf(n2, 1e-30f));
      vloc = w * rn;
      vsh[lane] = vloc;
      __syncthreads();
    }
  }
  if (lane == 0) ws[isoff + b] = rsqrtf(fmaxf(lambda, 1e-30f));  /* 1/sigma */
}

/* U_b = (Wv @ T_b) * inv_sigma_b  [512 x 64]; T chunk-reduced on load */
__global__ __launch_bounds__(256) void k_ufold(const float* __restrict__ Wv,
                                               float* __restrict__ ws, int nchunk)
{
  __shared__ float Wt[64][64];
  __shared__ float Tl[64][64];
  const int rt = blockIdx.x, b = blockIdx.y;
  const float* TP = ws + CPOFF + (size_t)(b*3+2)*nchunk*4096;
  const size_t isoff = (size_t)CPOFF + (size_t)B_*3*nchunk*4096;
  const size_t uoff  = isoff + 16;
  const float isig = ws[isoff + b];
  const int t = threadIdx.x;
  const int ti = t >> 4, tj = t & 15;
  for (int q = t; q < 1024; q += 256) {
    float4 s = {0.f,0.f,0.f,0.f};
    for (int ch = 0; ch < nchunk; ++ch) {
      const float4 p = *(reinterpret_cast<const float4*>(TP) + (size_t)ch*1024 + q);
      s.x+=p.x; s.y+=p.y; s.z+=p.z; s.w+=p.w;
    }
    *(reinterpret_cast<float4*>(&Tl[0][0]) + q) = s;
  }
  for (int q = t; q < 1024; q += 256) {
    const int row = q >> 4;
    const int c4  = (q & 15) * 4;
    const float4 wv = *reinterpret_cast<const float4*>(&Wv[(size_t)(rt*64+row)*64 + c4]);
    Wt[c4+0][row]=wv.x; Wt[c4+1][row]=wv.y; Wt[c4+2][row]=wv.z; Wt[c4+3][row]=wv.w;
  }
  __syncthreads();
  float acc[4][4] = {};
  #pragma unroll
  for (int c = 0; c < 64; ++c) {
    const float4 a  = *reinterpret_cast<const float4*>(&Wt[c][ti*4]);
    const float4 bb = *reinterpret_cast<const float4*>(&Tl[c][tj*4]);
    acc[0][0]+=a.x*bb.x; acc[0][1]+=a.x*bb.y; acc[0][2]+=a.x*bb.z; acc[0][3]+=a.x*bb.w;
    acc[1][0]+=a.y*bb.x; acc[1][1]+=a.y*bb.y; acc[1][2]+=a.y*bb.z; acc[1][3]+=a.y*bb.w;
    acc[2][0]+=a.z*bb.x; acc[2][1]+=a.z*bb.y; acc[2][2]+=a.z*bb.z; acc[2][3]+=a.z*bb.w;
    acc[3][0]+=a.w*bb.x; acc[3][1]+=a.w*bb.y; acc[3][2]+=a.w*bb.z; acc[3][3]+=a.w*bb.w;
  }
  #pragma unroll
  for (int i = 0; i < 4; ++i) {
    float4 o; o.x = acc[i][0]*isig; o.y = acc[i][1]*isig; o.z = acc[i][2]*isig; o.w = acc[i][3]*isig;
    *reinterpret_cast<float4*>(&ws[uoff + ((size_t)b*512 + rt*64 + ti*4+i)*64 + tj*4]) = o;
  }
}

/* out = U_b @ F_b + bv + x   per batch */
__global__ __launch_bounds__(256) void k_final(
    const float* __restrict__ x, const float* __restrict__ bv,
    float* __restrict__ out, const float* __restrict__ ws, int nchunk)
{
  __shared__ float Ut[64][64];
  __shared__ float Fl[64][64];
  const int nt = blockIdx.x, ot = blockIdx.y, b = blockIdx.z;
  const size_t uoff = (size_t)CPOFF + (size_t)B_*3*nchunk*4096 + 16;
  const float* scF = ws + SSOFF; const float* sfF = ws + SSOFF + 64;
  const int t = threadIdx.x;
  const int ti = t >> 4, tj = t & 15;
  for (int q = t; q < 1024; q += 256) {
    const int row = q >> 4;
    const int k4  = (q & 15) * 4;
    const float4 uv = *reinterpret_cast<const float4*>(
        &ws[uoff + ((size_t)b*512 + ot*64 + row)*64 + k4]);
    Ut[k4+0][row]=uv.x; Ut[k4+1][row]=uv.y; Ut[k4+2][row]=uv.z; Ut[k4+3][row]=uv.w;
  }
  for (int q = t; q < 1024; q += 256) {
    const int k  = q >> 4;
    const int c4 = (q & 15) * 4;
    const float4 yv = *reinterpret_cast<const float4*>(
        &ws[YOFF + (size_t)k*NCOL + b*1024 + nt*64 + c4]);
    const float s = scF[k], f = sfF[k];
    Fl[k][c4+0]=fmaxf(s*yv.x+f,0.f); Fl[k][c4+1]=fmaxf(s*yv.y+f,0.f);
    Fl[k][c4+2]=fmaxf(s*yv.z+f,0.f); Fl[k][c4+3]=fmaxf(s*yv.w+f,0.f);
  }
  __syncthreads();
  float acc[4][4] = {};
  #pragma unroll
  for (int k = 0; k < 64; ++k) {
    const float4 a  = *reinterpret_cast<const float4*>(&Ut[k][ti*4]);
    const float4 bb = *reinterpret_cast<const float4*>(&Fl[k][tj*4]);
    acc[0][0]+=a.x*bb.x; acc[0][1]+=a.x*bb.y; acc[0][2]+=a.x*bb.z; acc[0][3]+=a.x*bb.w;
    acc[1][0]+=a.y*bb.x; acc[1][1]+=a.y*bb.y; acc[1][2]+=a.y*bb.z; acc[1][3]+=a.y*bb.w;
    acc[2][0]+=a.z*bb.x; acc[2][1]+=a.z*bb.y; acc[2][2]+=a.z*bb.z; acc[2][3]+=a.z*bb.w;
    acc[3][0]+=a.w*bb.x; acc[3][1]+=a.w*bb.y; acc[3][2]+=a.w*bb.z; acc[3][3]+=a.w*bb.w;
  }
  #pragma unroll
  for (int i = 0; i < 4; ++i) {
    const int oc = ot*64 + ti*4 + i;
    const float bvv = bv[oc];
    const size_t base = ((size_t)b*C_ + oc)*HW_ + nt*64 + tj*4;
    const float4 xv = *reinterpret_cast<const float4*>(&x[base]);
    float4 o;
    o.x = acc[i][0]+bvv+xv.x; o.y = acc[i][1]+bvv+xv.y;
    o.z = acc[i][2]+bvv+xv.z; o.w = acc[i][3]+bvv+xv.w;
    *reinterpret_cast<float4*>(&out[base]) = o;
  }
}

extern "C" void kernel_launch(void* const* d_in, const int* in_sizes, int n_in,
                              void* d_out, int out_size, void* d_ws, size_t ws_size,
                              hipStream_t stream) {
  (void)in_sizes; (void)n_in; (void)out_size;
  const float* x       = (const float*)d_in[0];
  const float* Wf      = (const float*)d_in[1];
  const float* bf      = (const float*)d_in[2];
  const float* gamma_f = (const float*)d_in[3];
  const float* beta_f  = (const float*)d_in[4];
  const float* Wg      = (const float*)d_in[5];
  const float* bg      = (const float*)d_in[6];
  const float* gamma_g = (const float*)d_in[7];
  const float* beta_g  = (const float*)d_in[8];
  const float* Wh      = (const float*)d_in[9];
  const float* bh      = (const float*)d_in[10];
  const float* Wv      = (const float*)d_in[11];
  const float* bv      = (const float*)d_in[12];
  float* out = (float*)d_out;
  float* ws  = (float*)d_ws;

  /* adaptive chunk count: more chunks -> more cpart parallelism, more ws */
  auto need = [](int nc) -> size_t {
    return ((size_t)CPOFF + (size_t)B_*3*nc*4096 + 16 + (size_t)B_*512*64) * 4;
  };
  const int nchunk = (ws_size >= need(16)) ? 16 : (ws_size >= need(8)) ? 8 : 4;

  k_prep  <<<96,             256, 0, stream>>>(Wf, Wg, Wh, ws);
  k_conv  <<<256,            256, 0, stream>>>(x, bf, bg, bh, ws);
  k_stats <<<128,            256, 0, stream>>>(gamma_f, beta_f, gamma_g, beta_g, ws);
  k_cpart <<<dim3(nchunk,8), 256, 0, stream>>>(ws, nchunk);
  k_sigma <<<8,               64, 0, stream>>>(ws, nchunk);
  k_ufold <<<dim3(8,8),      256, 0, stream>>>(Wv, ws, nchunk);
  k_final <<<dim3(16,8,8),   256, 0, stream>>>(x, bv, out, ws, nchunk);
}

// Round 4
// 92.850 us; speedup vs baseline: 1.6026x; 1.6026x over previous
//
#include <hip/hip_runtime.h>

#define B_   8
#define C_   512
#define HW_  1024
#define MID_ 64
#define NCOL (B_*HW_)   /* 8192 */
#define NROWS 192
#define EPS  1e-5f

/* ws layout (float offsets) */
#define YOFF  0
#define YSZ   (NROWS*NCOL)            /* 1,572,864 f32 */
#define SSOFF (YOFF+YSZ)              /* scaleF[64] shiftF[64] scaleG[64] shiftG[64] */
#define SSSZ  256
#define WOFF  (SSOFF+SSSZ)            /* Whi[192*512]u16, Wlo[192*512]u16 = 98,304 floats */
#define WSZ   98304
#define CPOFF (WOFF+WSZ)              /* partials [8][3][nchunk][64][64] f32 */
/* cmoff = CPOFF + 8*3*nchunk*4096   : reduced [8][3][64][64]
   isoff = cmoff + 24*4096 ; uoff = isoff + 16 */

typedef unsigned short u16;
typedef __attribute__((ext_vector_type(8))) short short8;
typedef __attribute__((ext_vector_type(4))) float f32x4;

__device__ __forceinline__ u16 f2bf(float f) {
  unsigned u = __float_as_uint(f);
  unsigned r = u + 0x7fffu + ((u >> 16) & 1u);
  return (u16)(r >> 16);
}
__device__ __forceinline__ float bf2f(u16 h) {
  return __uint_as_float(((unsigned)h) << 16);
}
#define MFMA_B16(a,b,c) __builtin_amdgcn_mfma_f32_16x16x32_bf16(a,b,c,0,0,0)

/* ---- split W = [Wf;Wg;Wh] (192x512) into bf16 hi/lo in ws ---- */
__global__ __launch_bounds__(256) void k_prep(
    const float* __restrict__ Wf, const float* __restrict__ Wg,
    const float* __restrict__ Wh, float* __restrict__ ws)
{
  u16* Whi = (u16*)(ws + WOFF);
  u16* Wlo = Whi + NROWS*C_;
  const int e4 = blockIdx.x*256 + threadIdx.x;   /* 0..24575 */
  const int e  = e4*4;
  const int row = e >> 9, k = e & 511;
  const float* src = (row < 64) ? &Wf[row*C_ + k]
                   : (row < 128) ? &Wg[(row-64)*C_ + k]
                   : &Wh[(row-128)*C_ + k];
  const float4 v = *reinterpret_cast<const float4*>(src);
  u16 h0=f2bf(v.x), h1=f2bf(v.y), h2=f2bf(v.z), h3=f2bf(v.w);
  u16 l0=f2bf(v.x-bf2f(h0)), l1=f2bf(v.y-bf2f(h1)), l2=f2bf(v.z-bf2f(h2)), l3=f2bf(v.w-bf2f(h3));
  uint2 ph; ph.x = (unsigned)h0 | ((unsigned)h1<<16); ph.y = (unsigned)h2 | ((unsigned)h3<<16);
  uint2 pl; pl.x = (unsigned)l0 | ((unsigned)l1<<16); pl.y = (unsigned)l2 | ((unsigned)l3<<16);
  *reinterpret_cast<uint2*>(&Whi[e]) = ph;
  *reinterpret_cast<uint2*>(&Wlo[e]) = pl;
}

/* ---- Y[192][8192] = W @ X + bias, MFMA bf16x3 split ----
   grid: 256 blocks (32-col tiles), 256 thr (4 waves); wave w owns rows w*48..w*48+47 */
__global__ __launch_bounds__(256) void k_conv(
    const float* __restrict__ x,
    const float* __restrict__ bf, const float* __restrict__ bg, const float* __restrict__ bh,
    float* __restrict__ ws)
{
  __shared__ u16 Xh[8*32*8];   /* [kg][c][i] : x[kk+kg*8+i][n0+c] hi */
  __shared__ u16 Xl[8*32*8];
  const u16* Whi = (const u16*)(ws + WOFF);
  const u16* Wlo = Whi + NROWS*C_;
  const int n0  = blockIdx.x * 32;
  const int b   = n0 >> 10;
  const int hw0 = n0 & 1023;
  const int t   = threadIdx.x;
  const int lane = t & 63;
  const int wid  = t >> 6;
  const int wrow0 = wid * 48;
  const int cst  = t & 31;         /* staging col */
  const int kg2  = t >> 5;         /* staging k-group 0..7 */
  const int lm   = lane & 15;
  const int lk   = lane >> 4;

  f32x4 acc[3][2];
  #pragma unroll
  for (int i=0;i<3;++i) { acc[i][0]=(f32x4)0.f; acc[i][1]=(f32x4)0.f; }

  for (int kk = 0; kk < C_; kk += 64) {
    __syncthreads();
    {
      const float* xp = x + ((size_t)(b*C_ + kk + kg2*8))*HW_ + hw0 + cst;
      u16 hb[8], lb[8];
      #pragma unroll
      for (int i=0;i<8;++i) {
        const float v = xp[(size_t)i*HW_];
        hb[i] = f2bf(v); lb[i] = f2bf(v - bf2f(hb[i]));
      }
      uint4 ph, pl;
      ph.x=(unsigned)hb[0]|((unsigned)hb[1]<<16); ph.y=(unsigned)hb[2]|((unsigned)hb[3]<<16);
      ph.z=(unsigned)hb[4]|((unsigned)hb[5]<<16); ph.w=(unsigned)hb[6]|((unsigned)hb[7]<<16);
      pl.x=(unsigned)lb[0]|((unsigned)lb[1]<<16); pl.y=(unsigned)lb[2]|((unsigned)lb[3]<<16);
      pl.z=(unsigned)lb[4]|((unsigned)lb[5]<<16); pl.w=(unsigned)lb[6]|((unsigned)lb[7]<<16);
      *reinterpret_cast<uint4*>(&Xh[(kg2*32+cst)*8]) = ph;
      *reinterpret_cast<uint4*>(&Xl[(kg2*32+cst)*8]) = pl;
    }
    __syncthreads();
    #pragma unroll
    for (int kb = 0; kb < 2; ++kb) {
      short8 bhf[2], blf[2];
      #pragma unroll
      for (int nt = 0; nt < 2; ++nt) {
        const int col = nt*16 + lm;
        const int idx = ((kb*4 + lk)*32 + col)*8;
        bhf[nt] = *reinterpret_cast<const short8*>(&Xh[idx]);
        blf[nt] = *reinterpret_cast<const short8*>(&Xl[idx]);
      }
      #pragma unroll
      for (int mt = 0; mt < 3; ++mt) {
        const int row = wrow0 + mt*16 + lm;
        const size_t widx = (size_t)row*C_ + kk + kb*32 + lk*8;
        const short8 ah = *reinterpret_cast<const short8*>(&Whi[widx]);
        const short8 al = *reinterpret_cast<const short8*>(&Wlo[widx]);
        #pragma unroll
        for (int nt = 0; nt < 2; ++nt) {
          acc[mt][nt] = MFMA_B16(ah, bhf[nt], acc[mt][nt]);
          acc[mt][nt] = MFMA_B16(al, bhf[nt], acc[mt][nt]);
          acc[mt][nt] = MFMA_B16(ah, blf[nt], acc[mt][nt]);
        }
      }
    }
  }
  #pragma unroll
  for (int mt = 0; mt < 3; ++mt) {
    const int rbase = wrow0 + mt*16;
    const float* bp = (rbase < 64) ? bf : (rbase < 128) ? bg : bh;
    const int rloc0 = (rbase & 63) + lk*4;
    #pragma unroll
    for (int nt = 0; nt < 2; ++nt) {
      const int col = n0 + nt*16 + lm;
      #pragma unroll
      for (int r = 0; r < 4; ++r) {
        const int row = rbase + lk*4 + r;
        ws[YOFF + (size_t)row*NCOL + col] = acc[mt][nt][r] + bp[rloc0 + r];
      }
    }
  }
}

/* per-row mean/var over 8192 cols for rows 0..127, fold BN into scale/shift */
__global__ __launch_bounds__(256) void k_stats(
    const float* __restrict__ gamma_f, const float* __restrict__ beta_f,
    const float* __restrict__ gamma_g, const float* __restrict__ beta_g,
    float* __restrict__ ws)
{
  const int r = blockIdx.x;   /* 0..127 */
  const float4* Yr = reinterpret_cast<const float4*>(ws + YOFF + (size_t)r*NCOL);
  const int t = threadIdx.x;
  float s = 0.f, s2 = 0.f;
  for (int n = t; n < NCOL/4; n += 256) {
    const float4 v = Yr[n];
    s  += (v.x+v.y)+(v.z+v.w);
    s2 += (v.x*v.x+v.y*v.y)+(v.z*v.z+v.w*v.w);
  }
  __shared__ float sh[256], sh2[256];
  sh[t] = s; sh2[t] = s2;
  __syncthreads();
  for (int st = 128; st > 0; st >>= 1) {
    if (t < st) { sh[t] += sh[t+st]; sh2[t] += sh2[t+st]; }
    __syncthreads();
  }
  if (t == 0) {
    const float mean = sh[0] * (1.0f/NCOL);
    const float var  = sh2[0] * (1.0f/NCOL) - mean*mean;
    float g, be; int j;
    if (r < 64) { j = r;     g = gamma_f[j]; be = beta_f[j]; }
    else        { j = r-64;  g = gamma_g[j]; be = beta_g[j]; }
    const float sc = g * rsqrtf(var + EPS);
    const float sf = be - mean*sc;
    if (r < 64) { ws[SSOFF + j]       = sc; ws[SSOFF + 64  + j] = sf; }
    else        { ws[SSOFF + 128 + j] = sc; ws[SSOFF + 192 + j] = sf; }
  }
}

/* ---- fused Cf/Cg/T partials via MFMA bf16x3. ---- */
__global__ __launch_bounds__(256) void k_cpart(float* __restrict__ ws, int nchunk)
{
  __shared__ u16 Sh[3][64][72];
  __shared__ u16 Sl[3][64][72];
  const int chunk = blockIdx.x, b = blockIdx.y;
  const int chunkcols = 1024 / nchunk;
  const int bcol0 = b*1024 + chunk*chunkcols;
  const float* Y = ws + YOFF;
  const float* SS = ws + SSOFF;
  const int t = threadIdx.x;
  const int lane = t & 63, wid = t >> 6;
  const int lm = lane & 15, lk = lane >> 4;
  const int mt0 = (wid >> 1) * 2;
  const int nt0 = (wid & 1) * 2;

  f32x4 acc[3][2][2];
  #pragma unroll
  for (int p=0;p<3;++p) for (int i=0;i<2;++i) for (int j=0;j<2;++j) acc[p][i][j]=(f32x4)0.f;

  for (int kk = 0; kk < chunkcols; kk += 64) {
    __syncthreads();
    for (int q = t; q < 3072; q += 256) {
      const int mm = q >> 10, rem = q & 1023;
      const int r = rem >> 4, c4 = (rem & 15) * 4;
      const float4 v = *reinterpret_cast<const float4*>(
          &Y[(size_t)(mm*64 + r)*NCOL + bcol0 + kk + c4]);
      float v0, v1, v2, v3;
      if (mm < 2) {
        const float sc = SS[mm*128 + r], sf = SS[mm*128 + 64 + r];
        v0 = fmaxf(sc*v.x+sf, 0.f); v1 = fmaxf(sc*v.y+sf, 0.f);
        v2 = fmaxf(sc*v.z+sf, 0.f); v3 = fmaxf(sc*v.w+sf, 0.f);
      } else { v0=v.x; v1=v.y; v2=v.z; v3=v.w; }
      const u16 h0=f2bf(v0), h1=f2bf(v1), h2=f2bf(v2), h3=f2bf(v3);
      uint2 ph; ph.x=(unsigned)h0|((unsigned)h1<<16); ph.y=(unsigned)h2|((unsigned)h3<<16);
      uint2 pl;
      pl.x=(unsigned)f2bf(v0-bf2f(h0)) | ((unsigned)f2bf(v1-bf2f(h1))<<16);
      pl.y=(unsigned)f2bf(v2-bf2f(h2)) | ((unsigned)f2bf(v3-bf2f(h3))<<16);
      *reinterpret_cast<uint2*>(&Sh[mm][r][c4]) = ph;
      *reinterpret_cast<uint2*>(&Sl[mm][r][c4]) = pl;
    }
    __syncthreads();
    #pragma unroll
    for (int kb = 0; kb < 2; ++kb) {
      const int ko = kb*32 + lk*8;
      short8 ah[3][2], al[3][2];
      #pragma unroll
      for (int m = 0; m < 3; ++m)
        #pragma unroll
        for (int mi = 0; mi < 2; ++mi) {
          const int row = (mt0+mi)*16 + lm;
          ah[m][mi] = *reinterpret_cast<const short8*>(&Sh[m][row][ko]);
          al[m][mi] = *reinterpret_cast<const short8*>(&Sl[m][row][ko]);
        }
      short8 bhf[2][2], blf[2][2];
      #pragma unroll
      for (int m = 0; m < 2; ++m)
        #pragma unroll
        for (int ni = 0; ni < 2; ++ni) {
          const int row = (nt0+ni)*16 + lm;
          bhf[m][ni] = *reinterpret_cast<const short8*>(&Sh[m][row][ko]);
          blf[m][ni] = *reinterpret_cast<const short8*>(&Sl[m][row][ko]);
        }
      #pragma unroll
      for (int p = 0; p < 3; ++p) {
        const int am = p;
        const int bm = (p==0) ? 0 : 1;
        #pragma unroll
        for (int mi = 0; mi < 2; ++mi)
          #pragma unroll
          for (int ni = 0; ni < 2; ++ni) {
            acc[p][mi][ni] = MFMA_B16(ah[am][mi], bhf[bm][ni], acc[p][mi][ni]);
            acc[p][mi][ni] = MFMA_B16(al[am][mi], bhf[bm][ni], acc[p][mi][ni]);
            acc[p][mi][ni] = MFMA_B16(ah[am][mi], blf[bm][ni], acc[p][mi][ni]);
          }
      }
    }
  }
  float* cp = ws + CPOFF;
  #pragma unroll
  for (int p = 0; p < 3; ++p) {
    float* base = cp + ((size_t)((b*3+p)*nchunk + chunk))*4096;
    #pragma unroll
    for (int mi = 0; mi < 2; ++mi)
      #pragma unroll
      for (int ni = 0; ni < 2; ++ni) {
        const int col = (nt0+ni)*16 + lm;
        #pragma unroll
        for (int r = 0; r < 4; ++r) {
          const int row = (mt0+mi)*16 + lk*4 + r;
          base[(size_t)row*64 + col] = acc[p][mi][ni][r];
        }
      }
  }
}

/* ---- coalesced chunk reduction: partials -> CM [8][3][64][64] ----
   grid (4 qparts, 24 matrices) x 256 thr, one float4 per thread */
__global__ __launch_bounds__(256) void k_creduce(float* __restrict__ ws, int nchunk)
{
  const int m = blockIdx.y;                    /* b*3+p */
  const int q = blockIdx.x*256 + threadIdx.x;  /* 0..1023 float4 index */
  const float4* src = reinterpret_cast<const float4*>(ws + CPOFF) + (size_t)m*nchunk*1024;
  const size_t cmoff = (size_t)CPOFF + (size_t)B_*3*nchunk*4096;
  float4 s = {0.f,0.f,0.f,0.f};
  for (int ch = 0; ch < nchunk; ++ch) {
    const float4 p = src[(size_t)ch*1024 + q];
    s.x+=p.x; s.y+=p.y; s.z+=p.z; s.w+=p.w;
  }
  *(reinterpret_cast<float4*>(ws + cmoff) + (size_t)m*1024 + q) = s;
}

/* per batch: power iteration on M = Cg @ Cf (reduced CM inputs). */
__global__ __launch_bounds__(64) void k_sigma(float* __restrict__ ws, int nchunk)
{
  const int b = blockIdx.x;
  const int lane = threadIdx.x;
  const size_t cmoff = (size_t)CPOFF + (size_t)B_*3*nchunk*4096;
  const size_t isoff = cmoff + 24*4096;
  const float* Cf = ws + cmoff + (size_t)(b*3+0)*4096;
  const float* Cg = ws + cmoff + (size_t)(b*3+1)*4096;
  __shared__ float vsh[64];
  __shared__ float ush[64];
  float cfr[64], cgr[64];
  #pragma unroll
  for (int k4 = 0; k4 < 16; ++k4) {
    const float4 fa = *reinterpret_cast<const float4*>(&Cf[lane*64 + k4*4]);
    const float4 fc = *reinterpret_cast<const float4*>(&Cg[lane*64 + k4*4]);
    cfr[k4*4+0]=fa.x; cfr[k4*4+1]=fa.y; cfr[k4*4+2]=fa.z; cfr[k4*4+3]=fa.w;
    cgr[k4*4+0]=fc.x; cgr[k4*4+1]=fc.y; cgr[k4*4+2]=fc.z; cgr[k4*4+3]=fc.w;
  }
  float vloc = 0.125f;
  vsh[lane] = vloc;
  __syncthreads();
  float lambda = 0.f;
  #define NIT 20
  for (int it = 0; it <= NIT; ++it) {
    float u0=0.f,u1=0.f,u2=0.f,u3=0.f;
    #pragma unroll
    for (int j4 = 0; j4 < 16; ++j4) {
      const float4 vq = *reinterpret_cast<const float4*>(&vsh[j4*4]);
      u0 += cfr[j4*4+0]*vq.x; u1 += cfr[j4*4+1]*vq.y;
      u2 += cfr[j4*4+2]*vq.z; u3 += cfr[j4*4+3]*vq.w;
    }
    ush[lane] = (u0+u1)+(u2+u3);
    __syncthreads();
    float w0=0.f,w1=0.f,w2=0.f,w3=0.f;
    #pragma unroll
    for (int j4 = 0; j4 < 16; ++j4) {
      const float4 uq = *reinterpret_cast<const float4*>(&ush[j4*4]);
      w0 += cgr[j4*4+0]*uq.x; w1 += cgr[j4*4+1]*uq.y;
      w2 += cgr[j4*4+2]*uq.z; w3 += cgr[j4*4+3]*uq.w;
    }
    const float w = (w0+w1)+(w2+w3);
    if (it == NIT) {
      float num = vloc * w;
      #pragma unroll
      for (int off = 32; off > 0; off >>= 1) num += __shfl_xor(num, off);
      lambda = num;
    } else {
      float n2 = w*w;
      #pragma unroll
      for (int off = 32; off > 0; off >>= 1) n2 += __shfl_xor(n2, off);
      const float rn = rsqrtf(fmaxf(n2, 1e-30f));
      vloc = w * rn;
      vsh[lane] = vloc;
      __syncthreads();
    }
  }
  if (lane == 0) ws[isoff + b] = rsqrtf(fmaxf(lambda, 1e-30f));  /* 1/sigma */
}

/* U_b = (Wv @ T_b) * inv_sigma_b  [512 x 64]; T from reduced CM */
__global__ __launch_bounds__(256) void k_ufold(const float* __restrict__ Wv,
                                               float* __restrict__ ws, int nchunk)
{
  __shared__ float Wt[64][64];
  __shared__ float Tl[64][64];
  const int rt = blockIdx.x, b = blockIdx.y;
  const size_t cmoff = (size_t)CPOFF + (size_t)B_*3*nchunk*4096;
  const size_t isoff = cmoff + 24*4096;
  const size_t uoff  = isoff + 16;
  const float* T = ws + cmoff + (size_t)(b*3+2)*4096;
  const float isig = ws[isoff + b];
  const int t = threadIdx.x;
  const int ti = t >> 4, tj = t & 15;
  for (int q = t; q < 1024; q += 256)
    *(reinterpret_cast<float4*>(&Tl[0][0]) + q) = *(reinterpret_cast<const float4*>(T) + q);
  for (int q = t; q < 1024; q += 256) {
    const int row = q >> 4;
    const int c4  = (q & 15) * 4;
    const float4 wv = *reinterpret_cast<const float4*>(&Wv[(size_t)(rt*64+row)*64 + c4]);
    Wt[c4+0][row]=wv.x; Wt[c4+1][row]=wv.y; Wt[c4+2][row]=wv.z; Wt[c4+3][row]=wv.w;
  }
  __syncthreads();
  float acc[4][4] = {};
  #pragma unroll
  for (int c = 0; c < 64; ++c) {
    const float4 a  = *reinterpret_cast<const float4*>(&Wt[c][ti*4]);
    const float4 bb = *reinterpret_cast<const float4*>(&Tl[c][tj*4]);
    acc[0][0]+=a.x*bb.x; acc[0][1]+=a.x*bb.y; acc[0][2]+=a.x*bb.z; acc[0][3]+=a.x*bb.w;
    acc[1][0]+=a.y*bb.x; acc[1][1]+=a.y*bb.y; acc[1][2]+=a.y*bb.z; acc[1][3]+=a.y*bb.w;
    acc[2][0]+=a.z*bb.x; acc[2][1]+=a.z*bb.y; acc[2][2]+=a.z*bb.z; acc[2][3]+=a.z*bb.w;
    acc[3][0]+=a.w*bb.x; acc[3][1]+=a.w*bb.y; acc[3][2]+=a.w*bb.z; acc[3][3]+=a.w*bb.w;
  }
  #pragma unroll
  for (int i = 0; i < 4; ++i) {
    float4 o; o.x = acc[i][0]*isig; o.y = acc[i][1]*isig; o.z = acc[i][2]*isig; o.w = acc[i][3]*isig;
    *reinterpret_cast<float4*>(&ws[uoff + ((size_t)b*512 + rt*64 + ti*4+i)*64 + tj*4]) = o;
  }
}

/* out = U_b @ F_b + bv + x   per batch */
__global__ __launch_bounds__(256) void k_final(
    const float* __restrict__ x, const float* __restrict__ bv,
    float* __restrict__ out, const float* __restrict__ ws, int nchunk)
{
  __shared__ float Ut[64][64];
  __shared__ float Fl[64][64];
  const int nt = blockIdx.x, ot = blockIdx.y, b = blockIdx.z;
  const size_t uoff = (size_t)CPOFF + (size_t)B_*3*nchunk*4096 + 24*4096 + 16;
  const float* scF = ws + SSOFF; const float* sfF = ws + SSOFF + 64;
  const int t = threadIdx.x;
  const int ti = t >> 4, tj = t & 15;
  for (int q = t; q < 1024; q += 256) {
    const int row = q >> 4;
    const int k4  = (q & 15) * 4;
    const float4 uv = *reinterpret_cast<const float4*>(
        &ws[uoff + ((size_t)b*512 + ot*64 + row)*64 + k4]);
    Ut[k4+0][row]=uv.x; Ut[k4+1][row]=uv.y; Ut[k4+2][row]=uv.z; Ut[k4+3][row]=uv.w;
  }
  for (int q = t; q < 1024; q += 256) {
    const int k  = q >> 4;
    const int c4 = (q & 15) * 4;
    const float4 yv = *reinterpret_cast<const float4*>(
        &ws[YOFF + (size_t)k*NCOL + b*1024 + nt*64 + c4]);
    const float s = scF[k], f = sfF[k];
    Fl[k][c4+0]=fmaxf(s*yv.x+f,0.f); Fl[k][c4+1]=fmaxf(s*yv.y+f,0.f);
    Fl[k][c4+2]=fmaxf(s*yv.z+f,0.f); Fl[k][c4+3]=fmaxf(s*yv.w+f,0.f);
  }
  __syncthreads();
  float acc[4][4] = {};
  #pragma unroll
  for (int k = 0; k < 64; ++k) {
    const float4 a  = *reinterpret_cast<const float4*>(&Ut[k][ti*4]);
    const float4 bb = *reinterpret_cast<const float4*>(&Fl[k][tj*4]);
    acc[0][0]+=a.x*bb.x; acc[0][1]+=a.x*bb.y; acc[0][2]+=a.x*bb.z; acc[0][3]+=a.x*bb.w;
    acc[1][0]+=a.y*bb.x; acc[1][1]+=a.y*bb.y; acc[1][2]+=a.y*bb.z; acc[1][3]+=a.y*bb.w;
    acc[2][0]+=a.z*bb.x; acc[2][1]+=a.z*bb.y; acc[2][2]+=a.z*bb.z; acc[2][3]+=a.z*bb.w;
    acc[3][0]+=a.w*bb.x; acc[3][1]+=a.w*bb.y; acc[3][2]+=a.w*bb.z; acc[3][3]+=a.w*bb.w;
  }
  #pragma unroll
  for (int i = 0; i < 4; ++i) {
    const int oc = ot*64 + ti*4 + i;
    const float bvv = bv[oc];
    const size_t base = ((size_t)b*C_ + oc)*HW_ + nt*64 + tj*4;
    const float4 xv = *reinterpret_cast<const float4*>(&x[base]);
    float4 o;
    o.x = acc[i][0]+bvv+xv.x; o.y = acc[i][1]+bvv+xv.y;
    o.z = acc[i][2]+bvv+xv.z; o.w = acc[i][3]+bvv+xv.w;
    *reinterpret_cast<float4*>(&out[base]) = o;
  }
}

extern "C" void kernel_launch(void* const* d_in, const int* in_sizes, int n_in,
                              void* d_out, int out_size, void* d_ws, size_t ws_size,
                              hipStream_t stream) {
  (void)in_sizes; (void)n_in; (void)out_size;
  const float* x       = (const float*)d_in[0];
  const float* Wf      = (const float*)d_in[1];
  const float* bf      = (const float*)d_in[2];
  const float* gamma_f = (const float*)d_in[3];
  const float* beta_f  = (const float*)d_in[4];
  const float* Wg      = (const float*)d_in[5];
  const float* bg      = (const float*)d_in[6];
  const float* gamma_g = (const float*)d_in[7];
  const float* beta_g  = (const float*)d_in[8];
  const float* Wh      = (const float*)d_in[9];
  const float* bh      = (const float*)d_in[10];
  const float* Wv      = (const float*)d_in[11];
  const float* bv      = (const float*)d_in[12];
  float* out = (float*)d_out;
  float* ws  = (float*)d_ws;

  auto need = [](int nc) -> size_t {
    return ((size_t)CPOFF + (size_t)B_*3*nc*4096 + 24*4096 + 16 + (size_t)B_*512*64) * 4;
  };
  const int nchunk = (ws_size >= need(16)) ? 16 : (ws_size >= need(8)) ? 8 : 4;

  k_prep   <<<96,             256, 0, stream>>>(Wf, Wg, Wh, ws);
  k_conv   <<<256,            256, 0, stream>>>(x, bf, bg, bh, ws);
  k_stats  <<<128,            256, 0, stream>>>(gamma_f, beta_f, gamma_g, beta_g, ws);
  k_cpart  <<<dim3(nchunk,8), 256, 0, stream>>>(ws, nchunk);
  k_creduce<<<dim3(4,24),     256, 0, stream>>>(ws, nchunk);
  k_sigma  <<<8,               64, 0, stream>>>(ws, nchunk);
  k_ufold  <<<dim3(8,8),      256, 0, stream>>>(Wv, ws, nchunk);
  k_final  <<<dim3(16,8,8),   256, 0, stream>>>(x, bv, out, ws, nchunk);
}